// Round 5
// baseline (206.555 us; speedup 1.0000x reference)
//
#include <hip/hip_runtime.h>
#include <stdint.h>

typedef __attribute__((ext_vector_type(4))) float f32x4;
typedef __attribute__((ext_vector_type(8))) _Float16 f16x8;

#define HIDDEN 1024
#define SEQ 2048
#define NB 4

__device__ inline unsigned short f2h_bits(float f) {
    _Float16 h = (_Float16)f;
    return __builtin_bit_cast(unsigned short, h);
}

__device__ inline void gload16(const void* g, void* l) {
    __builtin_amdgcn_global_load_lds(
        (const __attribute__((address_space(1))) unsigned int*)g,
        (__attribute__((address_space(3))) unsigned int*)l,
        16, 0, 0);
}

template<int N> __device__ inline void waitvm() {
    if constexpr (N == 0) asm volatile("s_waitcnt vmcnt(0)" ::: "memory");
    else if constexpr (N == 2) asm volatile("s_waitcnt vmcnt(2)" ::: "memory");
    else if constexpr (N == 3) asm volatile("s_waitcnt vmcnt(3)" ::: "memory");
    else if constexpr (N == 4) asm volatile("s_waitcnt vmcnt(4)" ::: "memory");
    else if constexpr (N == 6) asm volatile("s_waitcnt vmcnt(6)" ::: "memory");
    else static_assert(N == 0, "bad vmcnt");
}
__device__ inline void waitlgkm0() { asm volatile("s_waitcnt lgkmcnt(0)" ::: "memory"); }

// ===================== 8-phase-style GEMM =====================
// C[M,N] = A[M,K] @ Bt[N,K]^T (+bias). fp16 in, f32 accum.
// 512 threads = 8 waves (2M x 4N). Wave tile (BM/2) x (BN/4).
// K-tile = 64 = 2 slices of 32; slice-major LDS, dbuf=2, counted vmcnt
// (never 0 except final tile). Swizzle: phys 16B slot = logical ^ ((row>>1)&3).
// T1: bijective XCD block swizzle (requires nwg % 8 == 0).
// BIAS_MODE: 0 none, 1 bias[col], 2 bias[row].
template<int BM, int BN, int BIAS_MODE, bool OUT_F16, int MINW>
__global__ __launch_bounds__(512, MINW) void gemm8p(
    const unsigned short* __restrict__ A, int lda,
    const unsigned short* __restrict__ Bt, int ldb,
    const float* __restrict__ bias,
    void* __restrict__ Cptr, int ldc, int K,
    long long aBatch, long long bBatch, long long cBatch)
{
    constexpr int MR = BM / 32;           // m-frags per wave
    constexpr int NRW = BN / 64;          // n-frags per wave
    constexpr int LA = BM / 128;          // A gloads/thread/slice
    constexpr int LB = BN / 128;
    constexpr int LP = LA + LB;           // loads per slice-pair
    constexpr int ASLICE = BM * 32;       // halfs per A slice
    constexpr int BSLICE = BN * 32;
    constexpr int BOFF = 4 * ASLICE;      // half-offset of B region

    extern __shared__ unsigned short lds[];

    const int tid = threadIdx.x, lane = tid & 63, wave = tid >> 6;
    const int wr = wave >> 2, wc = wave & 3;
    const int fr = lane & 15, fq = lane >> 4;

    // T1 XCD-bijective block swizzle over the flat grid
    const int gx = gridDim.x, gy = gridDim.y;
    const int nwg = gx * gy * gridDim.z;
    const int id = (blockIdx.z * gy + blockIdx.y) * gx + blockIdx.x;
    const int id2 = (id & 7) * (nwg >> 3) + (id >> 3);
    const int bx = id2 % gx;
    const int by = (id2 / gx) % gy;
    const long long bz = id2 / (gx * gy);

    const unsigned short* Ab = A + bz * aBatch + (long long)(by * BM) * lda;
    const unsigned short* Bb = Bt + bz * bBatch + (long long)(bx * BN) * ldb;

    // staging: chunk c = i*512+tid; row=c>>2, phys slot=c&3, logical=slot^((row>>1)&3)
    const unsigned short* sA[LA]; int dA[LA];
    #pragma unroll
    for (int i = 0; i < LA; ++i) {
        int c = i * 512 + tid; int r = c >> 2; int ls = (c & 3) ^ ((r >> 1) & 3);
        sA[i] = Ab + (long long)r * lda + ls * 8;
        dA[i] = (i * 512 + wave * 64) * 16;
    }
    const unsigned short* sB[LB]; int dB[LB];
    #pragma unroll
    for (int i = 0; i < LB; ++i) {
        int c = i * 512 + tid; int r = c >> 2; int ls = (c & 3) ^ ((r >> 1) & 3);
        sB[i] = Bb + (long long)r * ldb + ls * 8;
        dB[i] = (i * 512 + wave * 64) * 16;
    }

    auto stage = [&](int t, int ks) {
        int buf = t & 1;
        int aoff = ((buf * 2 + ks) * ASLICE) * 2;          // bytes
        int boff = (BOFF + (buf * 2 + ks) * BSLICE) * 2;
        int kof = t * 64 + ks * 32;
        #pragma unroll
        for (int i = 0; i < LA; ++i) gload16(sA[i] + kof, (char*)lds + aoff + dA[i]);
        #pragma unroll
        for (int i = 0; i < LB; ++i) gload16(sB[i] + kof, (char*)lds + boff + dB[i]);
    };

    const int NT = K / 64;
    // prologue: 3 slice-pairs in flight
    stage(0, 0); stage(0, 1); stage(1, 0);

    f32x4 acc[MR][NRW] = {};

    for (int t = 0; t < NT; ++t) {
        #pragma unroll
        for (int ks = 0; ks < 2; ++ks) {
            // gate on this slice-pair's loads (exact counts; never 0 except last tile)
            if (t == NT - 1) { if (ks == 0) waitvm<LP>(); else waitvm<0>(); }
            else waitvm<2 * LP>();
            __builtin_amdgcn_s_barrier();
            __builtin_amdgcn_sched_barrier(0);

            const int buf = t & 1;
            const unsigned short* as = lds + (buf * 2 + ks) * ASLICE;
            const unsigned short* bs = lds + BOFF + (buf * 2 + ks) * BSLICE;
            f16x8 af[MR], bf[NRW];
            #pragma unroll
            for (int m = 0; m < MR; ++m) {
                int r = wr * (BM / 2) + m * 16 + fr;
                int es = fq ^ ((r >> 1) & 3);
                af[m] = *(const f16x8*)&as[r * 32 + es * 8];
            }
            #pragma unroll
            for (int n = 0; n < NRW; ++n) {
                int r = wc * (BN / 4) + n * 16 + fr;
                int es = fq ^ ((r >> 1) & 3);
                bf[n] = *(const f16x8*)&bs[r * 32 + es * 8];
            }
            // staggered prefetch: (t,s0)->stage(t+1,s1); (t,s1)->stage(t+2,s0).
            if (ks == 0) { if (t + 1 < NT) stage(t + 1, 1); }
            else         { if (t + 2 < NT) stage(t + 2, 0); }

            waitlgkm0();
            __builtin_amdgcn_sched_barrier(0);
            __builtin_amdgcn_s_setprio(1);
            #pragma unroll
            for (int m = 0; m < MR; ++m)
                #pragma unroll
                for (int n = 0; n < NRW; ++n)
                    acc[m][n] = __builtin_amdgcn_mfma_f32_16x16x32_f16(af[m], bf[n], acc[m][n], 0, 0, 0);
            __builtin_amdgcn_s_setprio(0);
        }
    }

    // epilogue: C/D layout col=lane&15, row=(lane>>4)*4+i
    const int row0 = by * BM + wr * (BM / 2);
    const int col0 = bx * BN + wc * (BN / 4);
    #pragma unroll
    for (int m = 0; m < MR; ++m)
        #pragma unroll
        for (int n = 0; n < NRW; ++n)
            #pragma unroll
            for (int i = 0; i < 4; ++i) {
                int r = row0 + m * 16 + fq * 4 + i;
                int c = col0 + n * 16 + fr;
                float v = acc[m][n][i];
                if constexpr (BIAS_MODE == 1) v += bias[c];
                if constexpr (BIAS_MODE == 2) v += bias[r];
                if constexpr (OUT_F16)
                    ((unsigned short*)Cptr + bz * cBatch)[(long long)r * ldc + c] = f2h_bits(v);
                else
                    ((float*)Cptr + bz * cBatch)[(long long)r * ldc + c] = v;
            }
}

// ===================== small kernels =====================
__global__ __launch_bounds__(256) void cvt_f32_f16(const float* __restrict__ in,
                                                   unsigned short* __restrict__ out, int n8)
{
    int i = blockIdx.x * blockDim.x + threadIdx.x;
    if (i >= n8) return;
    const float4* p = (const float4*)in + (long long)i * 2;
    float4 a = p[0], b = p[1];
    ushort4 o0, o1;
    o0.x = f2h_bits(a.x); o0.y = f2h_bits(a.y); o0.z = f2h_bits(a.z); o0.w = f2h_bits(a.w);
    o1.x = f2h_bits(b.x); o1.y = f2h_bits(b.y); o1.z = f2h_bits(b.z); o1.w = f2h_bits(b.w);
    ushort4* o = (ushort4*)out + (long long)i * 2;
    o[0] = o0; o[1] = o1;
}

__global__ void transpose_cvt(const float* __restrict__ in, unsigned short* __restrict__ out,
                              int R, int C)
{
    __shared__ unsigned short t[32][33];
    const int bx = blockIdx.x * 32;
    const int by = blockIdx.y * 32;
    const int xT = threadIdx.x, yT = threadIdx.y;  // block (32,8)
    #pragma unroll
    for (int i = 0; i < 32; i += 8)
        t[yT + i][xT] = f2h_bits(in[(long long)(by + yT + i) * C + bx + xT]);
    __syncthreads();
    #pragma unroll
    for (int i = 0; i < 32; i += 8)
        out[(long long)(bx + yT + i) * R + by + xT] = t[xT][yT + i];
}

__global__ void concat_bias2(const float* __restrict__ bq, const float* __restrict__ bk,
                             float* __restrict__ cb)
{
    int i = threadIdx.x;  // 1024 threads
    cb[i] = bq[i];
    cb[HIDDEN + i] = bk[i];
}

// One block (256 threads) per row of 2048 f32 scores.
// Writes P (fp16 bits) in place over the first half of the same row.
__global__ __launch_bounds__(256) void softmax_inplace(float* __restrict__ S)
{
    const int tid = threadIdx.x;
    float* row = S + (long long)blockIdx.x * SEQ;
    float4 a = ((const float4*)row)[tid];
    float4 b = ((const float4*)row)[tid + 256];
    float vv[8] = {a.x, a.y, a.z, a.w, b.x, b.y, b.z, b.w};

    float mx = vv[0];
    #pragma unroll
    for (int j = 1; j < 8; ++j) mx = fmaxf(mx, vv[j]);
    #pragma unroll
    for (int o = 32; o > 0; o >>= 1) mx = fmaxf(mx, __shfl_xor(mx, o));
    __shared__ float redm[4], reds[4];
    if ((tid & 63) == 0) redm[tid >> 6] = mx;
    __syncthreads();
    mx = fmaxf(fmaxf(redm[0], redm[1]), fmaxf(redm[2], redm[3]));

    float ev[8], sum = 0.f;
    #pragma unroll
    for (int j = 0; j < 8; ++j) { ev[j] = __expf(vv[j] - mx); sum += ev[j]; }
    #pragma unroll
    for (int o = 32; o > 0; o >>= 1) sum += __shfl_xor(sum, o);
    if ((tid & 63) == 0) reds[tid >> 6] = sum;
    __syncthreads();
    sum = reds[0] + reds[1] + reds[2] + reds[3];
    float inv = 1.0f / sum;

    unsigned short* rb = (unsigned short*)row;
    ushort4 o0, o1;
    o0.x = f2h_bits(ev[0] * inv); o0.y = f2h_bits(ev[1] * inv);
    o0.z = f2h_bits(ev[2] * inv); o0.w = f2h_bits(ev[3] * inv);
    o1.x = f2h_bits(ev[4] * inv); o1.y = f2h_bits(ev[5] * inv);
    o1.z = f2h_bits(ev[6] * inv); o1.w = f2h_bits(ev[7] * inv);
    *(ushort4*)&rb[(long long)tid * 4] = o0;
    *(ushort4*)&rb[((long long)tid + 256) * 4] = o1;
}

// ===================== launch =====================
extern "C" void kernel_launch(void* const* d_in, const int* in_sizes, int n_in,
                              void* d_out, int out_size, void* d_ws, size_t ws_size,
                              hipStream_t stream)
{
    (void)in_sizes; (void)n_in; (void)out_size; (void)ws_size;
    const float* x  = (const float*)d_in[0];
    const float* Wq = (const float*)d_in[1];
    const float* bq = (const float*)d_in[2];
    const float* Wk = (const float*)d_in[3];
    const float* bk = (const float*)d_in[4];
    const float* Wv = (const float*)d_in[5];
    const float* bv = (const float*)d_in[6];
    float* out = (float*)d_out;

    (void)hipFuncSetAttribute(reinterpret_cast<const void*>(&gemm8p<128, 256, 1, true, 2>),
                              hipFuncAttributeMaxDynamicSharedMemorySize, 98304);
    (void)hipFuncSetAttribute(reinterpret_cast<const void*>(&gemm8p<128, 256, 2, true, 2>),
                              hipFuncAttributeMaxDynamicSharedMemorySize, 98304);
    (void)hipFuncSetAttribute(reinterpret_cast<const void*>(&gemm8p<128, 256, 0, false, 2>),
                              hipFuncAttributeMaxDynamicSharedMemorySize, 98304);
    (void)hipFuncSetAttribute(reinterpret_cast<const void*>(&gemm8p<128, 128, 0, false, 4>),
                              hipFuncAttributeMaxDynamicSharedMemorySize, 65536);

    char* ws = (char*)d_ws;
    const long long MTOT = (long long)NB * SEQ;  // 8192

    // Layout (83.886 MB total — fits the proven >=80 MiB ws):
    //  [0, 33.55M)      qk   [8192][2048] fp16
    //  [33.55, 50.33M)  vt   [1024][8192] fp16
    //  [50.33, 83.89M)  S-pair region: 2 x [2048][2048] f32.
    //    During projections this region holds wt (6.29M) + cb + xh (16.78M),
    //    all dead before the first S-gemm.
    unsigned short* qk = (unsigned short*)ws;
    unsigned short* vt = (unsigned short*)(ws + (size_t)MTOT * 2048 * 2);
    char* sreg = ws + (size_t)MTOT * 2048 * 2 + (size_t)HIDDEN * MTOT * 2;
    unsigned short* wt = (unsigned short*)sreg;
    float* cb = (float*)(sreg + (size_t)3 * HIDDEN * HIDDEN * 2);
    unsigned short* xh = (unsigned short*)(sreg + (size_t)3 * HIDDEN * HIDDEN * 2 + 8192);
    float* S = (float*)sreg;

    {
        int n8 = (int)(MTOT * HIDDEN / 8);
        cvt_f32_f16<<<dim3((n8 + 255) / 256), 256, 0, stream>>>(x, xh, n8);
    }
    dim3 tb(32, 8), tg(HIDDEN / 32, HIDDEN / 32);
    transpose_cvt<<<tg, tb, 0, stream>>>(Wq, wt,                       HIDDEN, HIDDEN);
    transpose_cvt<<<tg, tb, 0, stream>>>(Wk, wt +     HIDDEN * HIDDEN, HIDDEN, HIDDEN);
    transpose_cvt<<<tg, tb, 0, stream>>>(Wv, wt + 2 * HIDDEN * HIDDEN, HIDDEN, HIDDEN);
    concat_bias2<<<1, 1024, 0, stream>>>(bq, bk, cb);

    // qk[8192][2048] = xh @ [Wq|Wk] + [bq|bk]    (512 blocks)
    gemm8p<128, 256, 1, true, 2><<<dim3(2048 / 256, (unsigned)(MTOT / 128), 1), 512, 98304, stream>>>(
        xh, HIDDEN, wt, HIDDEN, cb, qk, 2048, HIDDEN, 0, 0, 0);

    // vt[1024][8192] = Wv^T @ xh^T + bv (row bias)    (256 blocks)
    gemm8p<128, 256, 2, true, 2><<<dim3((unsigned)(MTOT / 256), HIDDEN / 128, 1), 512, 98304, stream>>>(
        wt + 2 * HIDDEN * HIDDEN, HIDDEN, xh, HIDDEN, bv, vt, (int)MTOT, HIDDEN, 0, 0, 0);

    for (int b0 = 0; b0 < NB; b0 += 2) {
        const unsigned short* q  = qk + (long long)b0 * SEQ * 2048;
        const unsigned short* km = q + HIDDEN;
        // S = q @ k^T  (f32), z=2 -> 256 blocks
        gemm8p<128, 256, 0, false, 2><<<dim3(SEQ / 256, SEQ / 128, 2), 512, 98304, stream>>>(
            q, 2048, km, 2048, nullptr, S, SEQ, HIDDEN,
            (long long)SEQ * 2048, (long long)SEQ * 2048, (long long)SEQ * SEQ);
        // softmax rows, P fp16 in place (row stride becomes 4096 halfs)
        softmax_inplace<<<dim3(2 * SEQ), 256, 0, stream>>>(S);
        // O = P @ vt^T  (f32 straight to d_out), z=2 -> 256 blocks, 2 blocks/CU
        const unsigned short* P = (const unsigned short*)S;
        const unsigned short* Bv = vt + (long long)b0 * SEQ;
        float* Ob = out + (long long)b0 * SEQ * HIDDEN;
        gemm8p<128, 128, 0, false, 4><<<dim3(HIDDEN / 128, SEQ / 128, 2), 512, 65536, stream>>>(
            P, 2 * SEQ, Bv, (int)MTOT, nullptr, Ob, HIDDEN, SEQ,
            (long long)SEQ * 2 * SEQ, (long long)SEQ, (long long)SEQ * HIDDEN);
    }
}

// Round 6
// 202.034 us; speedup vs baseline: 1.0224x; 1.0224x over previous
//
#include <hip/hip_runtime.h>
#include <stdint.h>

typedef __attribute__((ext_vector_type(4))) float f32x4;
typedef __attribute__((ext_vector_type(8))) _Float16 f16x8;

#define HIDDEN 1024
#define SEQ 2048
#define NB 4

__device__ inline unsigned short f2h_bits(float f) {
    _Float16 h = (_Float16)f;
    return __builtin_bit_cast(unsigned short, h);
}

__device__ inline void gload16(const void* g, void* l) {
    __builtin_amdgcn_global_load_lds(
        (const __attribute__((address_space(1))) unsigned int*)g,
        (__attribute__((address_space(3))) unsigned int*)l,
        16, 0, 0);
}

template<int N> __device__ inline void waitvm() {
    if constexpr (N == 0) asm volatile("s_waitcnt vmcnt(0)" ::: "memory");
    else if constexpr (N == 3) asm volatile("s_waitcnt vmcnt(3)" ::: "memory");
    else if constexpr (N == 4) asm volatile("s_waitcnt vmcnt(4)" ::: "memory");
    else if constexpr (N == 6) asm volatile("s_waitcnt vmcnt(6)" ::: "memory");
    else if constexpr (N == 8) asm volatile("s_waitcnt vmcnt(8)" ::: "memory");
    else static_assert(N == 0, "bad vmcnt");
}
__device__ inline void waitlgkm0() { asm volatile("s_waitcnt lgkmcnt(0)" ::: "memory"); }

// ===================== phase-split pipelined GEMM =====================
// C[M,N] = A[M,K] @ Bt[N,K]^T (+bias). fp16 in, f32 accum.
// Wave grid WM x WN (THREADS = WM*WN*64); wave tile (BM/WM) x (BN/WN).
// K processed in 32-wide slices; slice-major LDS ring of 4 slots (A and B),
// swizzle: phys 16B slot = logical ^ ((row>>1)&3)  (involution, 0 conflicts
// measured). Staging distance 3 slice-pairs; one counted vmcnt gate per pair
// (exact LP / 0 only at the final two pairs).
// Each slice = 2 phases: ph0 {read B + A-half0, stage, barrier, 16(MH*NRW)
// MFMA}, ph1 {read A-half1 under ph0's MFMA shadow, barrier, MFMA}.
// T1: bijective XCD block swizzle (requires nwg % 8 == 0).
// BIAS_MODE: 0 none, 1 bias[col], 2 bias[row].
template<int BM, int BN, int WM, int WN, int BIAS_MODE, bool OUT_F16, int MINW>
__global__ __launch_bounds__(WM * WN * 64, MINW) void gemm8p(
    const unsigned short* __restrict__ A, int lda,
    const unsigned short* __restrict__ Bt, int ldb,
    const float* __restrict__ bias,
    void* __restrict__ Cptr, int ldc, int K,
    long long aBatch, long long bBatch, long long cBatch)
{
    constexpr int THREADS = WM * WN * 64;
    constexpr int MR = BM / (WM * 16);    // m-frags per wave
    constexpr int NRW = BN / (WN * 16);   // n-frags per wave
    constexpr int MH = MR / 2;
    constexpr int LA = 4 * BM / THREADS;  // A gloads/thread/slice
    constexpr int LB = 4 * BN / THREADS;
    constexpr int LP = LA + LB;           // loads per slice-pair
    constexpr int ASLICE = BM * 32;       // halfs per A slice
    constexpr int BSLICE = BN * 32;
    constexpr int BOFF = 4 * ASLICE;      // half-offset of B region

    extern __shared__ unsigned short lds[];

    const int tid = threadIdx.x, lane = tid & 63, wave = tid >> 6;
    const int wr = wave / WN, wc = wave % WN;
    const int fr = lane & 15, fq = lane >> 4;

    // T1 XCD-bijective block swizzle over the flat grid
    const int gx = gridDim.x, gy = gridDim.y;
    const int nwg = gx * gy * gridDim.z;
    const int id = (blockIdx.z * gy + blockIdx.y) * gx + blockIdx.x;
    const int id2 = (id & 7) * (nwg >> 3) + (id >> 3);
    const int bx = id2 % gx;
    const int by = (id2 / gx) % gy;
    const long long bz = id2 / (gx * gy);

    const unsigned short* Ab = A + bz * aBatch + (long long)(by * BM) * lda;
    const unsigned short* Bb = Bt + bz * bBatch + (long long)(bx * BN) * ldb;

    // staging: chunk c = i*THREADS+tid; row=c>>2, phys slot=c&3,
    // logical slot = phys ^ ((row>>1)&3)  -> pre-inverse-swizzled source
    const unsigned short* sA[LA]; int dA[LA];
    #pragma unroll
    for (int i = 0; i < LA; ++i) {
        int c = i * THREADS + tid; int r = c >> 2; int ls = (c & 3) ^ ((r >> 1) & 3);
        sA[i] = Ab + (long long)r * lda + ls * 8;
        dA[i] = (i * THREADS + wave * 64) * 16;
    }
    const unsigned short* sB[LB]; int dB[LB];
    #pragma unroll
    for (int i = 0; i < LB; ++i) {
        int c = i * THREADS + tid; int r = c >> 2; int ls = (c & 3) ^ ((r >> 1) & 3);
        sB[i] = Bb + (long long)r * ldb + ls * 8;
        dB[i] = (i * THREADS + wave * 64) * 16;
    }

    auto stage = [&](int q) {   // stage slice-pair q (A+B slices, ring slot q&3)
        int slot = q & 3;
        int kof = q * 32;
        #pragma unroll
        for (int i = 0; i < LA; ++i)
            gload16(sA[i] + kof, (char*)lds + slot * (ASLICE * 2) + dA[i]);
        #pragma unroll
        for (int i = 0; i < LB; ++i)
            gload16(sB[i] + kof, (char*)lds + (BOFF + slot * BSLICE) * 2 + dB[i]);
    };

    const int NPAIR = K / 32;
    stage(0); stage(1); stage(2);    // 3 slice-pairs in flight

    f32x4 acc[MR][NRW] = {};

    for (int p = 0; p < NPAIR; ++p) {
        // gate: drain slice-pair p exactly; leave later pairs in flight
        if (p == NPAIR - 1) waitvm<0>();
        else if (p == NPAIR - 2) waitvm<LP>();
        else waitvm<2 * LP>();
        __builtin_amdgcn_s_barrier();
        __builtin_amdgcn_sched_barrier(0);

        const int slot = p & 3;
        const unsigned short* as = lds + slot * ASLICE;
        const unsigned short* bs = lds + BOFF + slot * BSLICE;

        f16x8 af[MR], bf[NRW];
        #pragma unroll
        for (int n = 0; n < NRW; ++n) {
            int r = wc * (BN / WN) + n * 16 + fr;
            int es = fq ^ ((r >> 1) & 3);
            bf[n] = *(const f16x8*)&bs[r * 32 + es * 8];
        }
        #pragma unroll
        for (int m = 0; m < MH; ++m) {
            int r = wr * (BM / WM) + m * 16 + fr;
            int es = fq ^ ((r >> 1) & 3);
            af[m] = *(const f16x8*)&as[r * 32 + es * 8];
        }
        if (p + 3 < NPAIR) stage(p + 3);   // WAR-safe: slot (p+3)&3 == (p-1)&3,
                                           // all reads of pair p-1 done pre-barrier
        waitlgkm0();
        __builtin_amdgcn_sched_barrier(0);
        __builtin_amdgcn_s_setprio(1);
        #pragma unroll
        for (int m = 0; m < MH; ++m)
            #pragma unroll
            for (int n = 0; n < NRW; ++n)
                acc[m][n] = __builtin_amdgcn_mfma_f32_16x16x32_f16(af[m], bf[n], acc[m][n], 0, 0, 0);
        __builtin_amdgcn_s_setprio(0);

        // ph1: A-half1 reads issue under ph0's MFMA shadow
        #pragma unroll
        for (int m = MH; m < MR; ++m) {
            int r = wr * (BM / WM) + m * 16 + fr;
            int es = fq ^ ((r >> 1) & 3);
            af[m] = *(const f16x8*)&as[r * 32 + es * 8];
        }
        __builtin_amdgcn_s_barrier();
        waitlgkm0();
        __builtin_amdgcn_sched_barrier(0);
        __builtin_amdgcn_s_setprio(1);
        #pragma unroll
        for (int m = MH; m < MR; ++m)
            #pragma unroll
            for (int n = 0; n < NRW; ++n)
                acc[m][n] = __builtin_amdgcn_mfma_f32_16x16x32_f16(af[m], bf[n], acc[m][n], 0, 0, 0);
        __builtin_amdgcn_s_setprio(0);
    }

    // epilogue: C/D layout col=lane&15, row=(lane>>4)*4+i
    const int row0 = by * BM + wr * (BM / WM);
    const int col0 = bx * BN + wc * (BN / WN);
    #pragma unroll
    for (int m = 0; m < MR; ++m)
        #pragma unroll
        for (int n = 0; n < NRW; ++n)
            #pragma unroll
            for (int i = 0; i < 4; ++i) {
                int r = row0 + m * 16 + fq * 4 + i;
                int c = col0 + n * 16 + fr;
                float v = acc[m][n][i];
                if constexpr (BIAS_MODE == 1) v += bias[c];
                if constexpr (BIAS_MODE == 2) v += bias[r];
                if constexpr (OUT_F16)
                    ((unsigned short*)Cptr + bz * cBatch)[(long long)r * ldc + c] = f2h_bits(v);
                else
                    ((float*)Cptr + bz * cBatch)[(long long)r * ldc + c] = v;
            }
}

// ===================== small kernels =====================
__global__ __launch_bounds__(256) void cvt_f32_f16(const float* __restrict__ in,
                                                   unsigned short* __restrict__ out, int n8)
{
    int i = blockIdx.x * blockDim.x + threadIdx.x;
    if (i >= n8) return;
    const float4* p = (const float4*)in + (long long)i * 2;
    float4 a = p[0], b = p[1];
    ushort4 o0, o1;
    o0.x = f2h_bits(a.x); o0.y = f2h_bits(a.y); o0.z = f2h_bits(a.z); o0.w = f2h_bits(a.w);
    o1.x = f2h_bits(b.x); o1.y = f2h_bits(b.y); o1.z = f2h_bits(b.z); o1.w = f2h_bits(b.w);
    ushort4* o = (ushort4*)out + (long long)i * 2;
    o[0] = o0; o[1] = o1;
}

__global__ void transpose_cvt(const float* __restrict__ in, unsigned short* __restrict__ out,
                              int R, int C)
{
    __shared__ unsigned short t[32][33];
    const int bx = blockIdx.x * 32;
    const int by = blockIdx.y * 32;
    const int xT = threadIdx.x, yT = threadIdx.y;  // block (32,8)
    #pragma unroll
    for (int i = 0; i < 32; i += 8)
        t[yT + i][xT] = f2h_bits(in[(long long)(by + yT + i) * C + bx + xT]);
    __syncthreads();
    #pragma unroll
    for (int i = 0; i < 32; i += 8)
        out[(long long)(bx + yT + i) * R + by + xT] = t[xT][yT + i];
}

__global__ void concat_bias2(const float* __restrict__ bq, const float* __restrict__ bk,
                             float* __restrict__ cb)
{
    int i = threadIdx.x;  // 1024 threads
    cb[i] = bq[i];
    cb[HIDDEN + i] = bk[i];
}

// One block (256 threads) per row of 2048 f32 scores.
// Writes P (fp16 bits) in place over the first half of the same row.
__global__ __launch_bounds__(256) void softmax_inplace(float* __restrict__ S)
{
    const int tid = threadIdx.x;
    float* row = S + (long long)blockIdx.x * SEQ;
    float4 a = ((const float4*)row)[tid];
    float4 b = ((const float4*)row)[tid + 256];
    float vv[8] = {a.x, a.y, a.z, a.w, b.x, b.y, b.z, b.w};

    float mx = vv[0];
    #pragma unroll
    for (int j = 1; j < 8; ++j) mx = fmaxf(mx, vv[j]);
    #pragma unroll
    for (int o = 32; o > 0; o >>= 1) mx = fmaxf(mx, __shfl_xor(mx, o));
    __shared__ float redm[4], reds[4];
    if ((tid & 63) == 0) redm[tid >> 6] = mx;
    __syncthreads();
    mx = fmaxf(fmaxf(redm[0], redm[1]), fmaxf(redm[2], redm[3]));

    float ev[8], sum = 0.f;
    #pragma unroll
    for (int j = 0; j < 8; ++j) { ev[j] = __expf(vv[j] - mx); sum += ev[j]; }
    #pragma unroll
    for (int o = 32; o > 0; o >>= 1) sum += __shfl_xor(sum, o);
    if ((tid & 63) == 0) reds[tid >> 6] = sum;
    __syncthreads();
    sum = reds[0] + reds[1] + reds[2] + reds[3];
    float inv = 1.0f / sum;

    unsigned short* rb = (unsigned short*)row;
    ushort4 o0, o1;
    o0.x = f2h_bits(ev[0] * inv); o0.y = f2h_bits(ev[1] * inv);
    o0.z = f2h_bits(ev[2] * inv); o0.w = f2h_bits(ev[3] * inv);
    o1.x = f2h_bits(ev[4] * inv); o1.y = f2h_bits(ev[5] * inv);
    o1.z = f2h_bits(ev[6] * inv); o1.w = f2h_bits(ev[7] * inv);
    *(ushort4*)&rb[(long long)tid * 4] = o0;
    *(ushort4*)&rb[((long long)tid + 256) * 4] = o1;
}

// ===================== launch =====================
extern "C" void kernel_launch(void* const* d_in, const int* in_sizes, int n_in,
                              void* d_out, int out_size, void* d_ws, size_t ws_size,
                              hipStream_t stream)
{
    (void)in_sizes; (void)n_in; (void)out_size; (void)ws_size;
    const float* x  = (const float*)d_in[0];
    const float* Wq = (const float*)d_in[1];
    const float* bq = (const float*)d_in[2];
    const float* Wk = (const float*)d_in[3];
    const float* bk = (const float*)d_in[4];
    const float* Wv = (const float*)d_in[5];
    const float* bv = (const float*)d_in[6];
    float* out = (float*)d_out;

    // variants: proj 256x256 (8 waves, 128KB), vt/S 128x256 (8 waves, 96KB),
    // O 128x128 (4 waves, 64KB, 2 blocks/CU)
    (void)hipFuncSetAttribute(reinterpret_cast<const void*>(&gemm8p<256, 256, 2, 4, 1, true, 2>),
                              hipFuncAttributeMaxDynamicSharedMemorySize, 131072);
    (void)hipFuncSetAttribute(reinterpret_cast<const void*>(&gemm8p<128, 256, 2, 4, 2, true, 2>),
                              hipFuncAttributeMaxDynamicSharedMemorySize, 98304);
    (void)hipFuncSetAttribute(reinterpret_cast<const void*>(&gemm8p<128, 256, 2, 4, 0, false, 2>),
                              hipFuncAttributeMaxDynamicSharedMemorySize, 98304);
    (void)hipFuncSetAttribute(reinterpret_cast<const void*>(&gemm8p<128, 128, 2, 2, 0, false, 2>),
                              hipFuncAttributeMaxDynamicSharedMemorySize, 65536);

    char* ws = (char*)d_ws;
    const long long MTOT = (long long)NB * SEQ;  // 8192

    // Layout (83.886 MB total — fits proven ws):
    //  [0, 33.55M)      qk   [8192][2048] fp16
    //  [33.55, 50.33M)  vt   [1024][8192] fp16
    //  [50.33, 83.89M)  S-pair region: 2 x [2048][2048] f32.
    //    During projections this region holds wt (6.29M) + cb + xh (16.78M).
    unsigned short* qk = (unsigned short*)ws;
    unsigned short* vt = (unsigned short*)(ws + (size_t)MTOT * 2048 * 2);
    char* sreg = ws + (size_t)MTOT * 2048 * 2 + (size_t)HIDDEN * MTOT * 2;
    unsigned short* wt = (unsigned short*)sreg;
    float* cb = (float*)(sreg + (size_t)3 * HIDDEN * HIDDEN * 2);
    unsigned short* xh = (unsigned short*)(sreg + (size_t)3 * HIDDEN * HIDDEN * 2 + 8192);
    float* S = (float*)sreg;

    {
        int n8 = (int)(MTOT * HIDDEN / 8);
        cvt_f32_f16<<<dim3((n8 + 255) / 256), 256, 0, stream>>>(x, xh, n8);
    }
    dim3 tb(32, 8), tg(HIDDEN / 32, HIDDEN / 32);
    transpose_cvt<<<tg, tb, 0, stream>>>(Wq, wt,                       HIDDEN, HIDDEN);
    transpose_cvt<<<tg, tb, 0, stream>>>(Wk, wt +     HIDDEN * HIDDEN, HIDDEN, HIDDEN);
    transpose_cvt<<<tg, tb, 0, stream>>>(Wv, wt + 2 * HIDDEN * HIDDEN, HIDDEN, HIDDEN);
    concat_bias2<<<1, 1024, 0, stream>>>(bq, bk, cb);

    // qk[8192][2048] = xh @ [Wq|Wk] + [bq|bk]   (256 blocks, 256^2 tile)
    gemm8p<256, 256, 2, 4, 1, true, 2><<<dim3(2048 / 256, (unsigned)(MTOT / 256), 1), 512, 131072, stream>>>(
        xh, HIDDEN, wt, HIDDEN, cb, qk, 2048, HIDDEN, 0, 0, 0);

    // vt[1024][8192] = Wv^T @ xh^T + bv (row bias)   (256 blocks)
    gemm8p<128, 256, 2, 4, 2, true, 2><<<dim3((unsigned)(MTOT / 256), HIDDEN / 128, 1), 512, 98304, stream>>>(
        wt + 2 * HIDDEN * HIDDEN, HIDDEN, xh, HIDDEN, bv, vt, (int)MTOT, HIDDEN, 0, 0, 0);

    for (int b0 = 0; b0 < NB; b0 += 2) {
        const unsigned short* q  = qk + (long long)b0 * SEQ * 2048;
        const unsigned short* km = q + HIDDEN;
        // S = q @ k^T  (f32), z=2 -> 256 blocks
        gemm8p<128, 256, 2, 4, 0, false, 2><<<dim3(SEQ / 256, SEQ / 128, 2), 512, 98304, stream>>>(
            q, 2048, km, 2048, nullptr, S, SEQ, HIDDEN,
            (long long)SEQ * 2048, (long long)SEQ * 2048, (long long)SEQ * SEQ);
        // softmax rows, P fp16 in place (row stride becomes 4096 halfs)
        softmax_inplace<<<dim3(2 * SEQ), 256, 0, stream>>>(S);
        // O = P @ vt^T  (f32 straight to d_out), z=2 -> 256 blocks, 2 blocks/CU
        const unsigned short* P = (const unsigned short*)S;
        const unsigned short* Bv = vt + (long long)b0 * SEQ;
        float* Ob = out + (long long)b0 * SEQ * HIDDEN;
        gemm8p<128, 128, 2, 2, 0, false, 2><<<dim3(HIDDEN / 128, SEQ / 128, 2), 256, 65536, stream>>>(
            P, 2 * SEQ, Bv, (int)MTOT, nullptr, Ob, HIDDEN, SEQ,
            (long long)SEQ * 2 * SEQ, (long long)SEQ, (long long)SEQ * HIDDEN);
    }
}

// Round 7
// 173.215 us; speedup vs baseline: 1.1925x; 1.1664x over previous
//
#include <hip/hip_runtime.h>
#include <stdint.h>

typedef __attribute__((ext_vector_type(4))) float f32x4;
typedef __attribute__((ext_vector_type(8))) _Float16 f16x8;
typedef __attribute__((ext_vector_type(8))) unsigned short u16x8;

#define HIDDEN 1024
#define SEQ 2048
#define NB 4

__device__ inline unsigned short f2h_bits(float f) {
    _Float16 h = (_Float16)f;
    return __builtin_bit_cast(unsigned short, h);
}
__device__ inline float h2f(unsigned short u) {
    return (float)__builtin_bit_cast(_Float16, u);
}

__device__ inline void gload16(const void* g, void* l) {
    __builtin_amdgcn_global_load_lds(
        (const __attribute__((address_space(1))) unsigned int*)g,
        (__attribute__((address_space(3))) unsigned int*)l,
        16, 0, 0);
}

template<int N> __device__ inline void waitvm() {
    if constexpr (N == 0) asm volatile("s_waitcnt vmcnt(0)" ::: "memory");
    else if constexpr (N == 3) asm volatile("s_waitcnt vmcnt(3)" ::: "memory");
    else if constexpr (N == 4) asm volatile("s_waitcnt vmcnt(4)" ::: "memory");
    else if constexpr (N == 6) asm volatile("s_waitcnt vmcnt(6)" ::: "memory");
    else if constexpr (N == 8) asm volatile("s_waitcnt vmcnt(8)" ::: "memory");
    else static_assert(N == 0, "bad vmcnt");
}
template<int N> __device__ inline void waitlgkm() {
    if constexpr (N == 0) asm volatile("s_waitcnt lgkmcnt(0)" ::: "memory");
    else if constexpr (N == 2) asm volatile("s_waitcnt lgkmcnt(2)" ::: "memory");
    else if constexpr (N == 4) asm volatile("s_waitcnt lgkmcnt(4)" ::: "memory");
    else static_assert(N == 0, "bad lgkmcnt");
}

// ===================== phase-split pipelined GEMM =====================
// C[M,N] = A[M,K] @ Bt[N,K]^T (+bias). fp16 in, f32 accum.
// Wave grid WM x WN; wave tile (BM/WM) x (BN/WN). K in 32-slices; slice-major
// LDS ring of 4 slots; swizzle phys-16B-slot = logical ^ ((row>>1)&3) (0
// conflicts measured). Staging distance 3; one counted vmcnt per slice.
// ONE barrier per slice; ph0 MFMA gated by lgkmcnt(MR-MH) so ph1's A-reads
// overlap ph0's MFMA; ph1 gated by lgkmcnt(0).
// T1: bijective XCD block swizzle (requires nwg % 8 == 0).
// BIAS_MODE: 0 none, 1 bias[col], 2 bias[row].
template<int BM, int BN, int WM, int WN, int BIAS_MODE, bool OUT_F16, int MINW>
__global__ __launch_bounds__(WM * WN * 64, MINW) void gemm8p(
    const unsigned short* __restrict__ A, int lda,
    const unsigned short* __restrict__ Bt, int ldb,
    const float* __restrict__ bias,
    void* __restrict__ Cptr, int ldc, int K,
    long long aBatch, long long bBatch, long long cBatch)
{
    constexpr int THREADS = WM * WN * 64;
    constexpr int MR = BM / (WM * 16);    // m-frags per wave
    constexpr int NRW = BN / (WN * 16);   // n-frags per wave
    constexpr int MH = MR / 2;
    constexpr int LA = 4 * BM / THREADS;  // A gloads/thread/slice
    constexpr int LB = 4 * BN / THREADS;
    constexpr int LP = LA + LB;           // loads per slice-pair
    constexpr int ASLICE = BM * 32;       // halfs per A slice
    constexpr int BSLICE = BN * 32;
    constexpr int BOFF = 4 * ASLICE;      // half-offset of B region

    extern __shared__ unsigned short lds[];

    const int tid = threadIdx.x, lane = tid & 63, wave = tid >> 6;
    const int wr = wave / WN, wc = wave % WN;
    const int fr = lane & 15, fq = lane >> 4;

    // T1 XCD-bijective block swizzle over the flat grid
    const int gx = gridDim.x, gy = gridDim.y;
    const int nwg = gx * gy * gridDim.z;
    const int id = (blockIdx.z * gy + blockIdx.y) * gx + blockIdx.x;
    const int id2 = (id & 7) * (nwg >> 3) + (id >> 3);
    const int bx = id2 % gx;
    const int by = (id2 / gx) % gy;
    const long long bz = id2 / (gx * gy);

    const unsigned short* Ab = A + bz * aBatch + (long long)(by * BM) * lda;
    const unsigned short* Bb = Bt + bz * bBatch + (long long)(bx * BN) * ldb;

    // staging: chunk c = i*THREADS+tid; row=c>>2, phys slot=c&3,
    // logical slot = phys ^ ((row>>1)&3)  -> pre-inverse-swizzled source
    const unsigned short* sA[LA]; int dA[LA];
    #pragma unroll
    for (int i = 0; i < LA; ++i) {
        int c = i * THREADS + tid; int r = c >> 2; int ls = (c & 3) ^ ((r >> 1) & 3);
        sA[i] = Ab + (long long)r * lda + ls * 8;
        dA[i] = (i * THREADS + wave * 64) * 16;
    }
    const unsigned short* sB[LB]; int dB[LB];
    #pragma unroll
    for (int i = 0; i < LB; ++i) {
        int c = i * THREADS + tid; int r = c >> 2; int ls = (c & 3) ^ ((r >> 1) & 3);
        sB[i] = Bb + (long long)r * ldb + ls * 8;
        dB[i] = (i * THREADS + wave * 64) * 16;
    }

    auto stage = [&](int q) {   // stage slice-pair q (A+B slices, ring slot q&3)
        int slot = q & 3;
        int kof = q * 32;
        #pragma unroll
        for (int i = 0; i < LA; ++i)
            gload16(sA[i] + kof, (char*)lds + slot * (ASLICE * 2) + dA[i]);
        #pragma unroll
        for (int i = 0; i < LB; ++i)
            gload16(sB[i] + kof, (char*)lds + (BOFF + slot * BSLICE) * 2 + dB[i]);
    };

    const int NPAIR = K / 32;
    stage(0); stage(1); stage(2);    // 3 slice-pairs in flight

    f32x4 acc[MR][NRW] = {};

    for (int p = 0; p < NPAIR; ++p) {
        // gate: drain slice-pair p exactly; leave later pairs in flight
        if (p == NPAIR - 1) waitvm<0>();
        else if (p == NPAIR - 2) waitvm<LP>();
        else waitvm<2 * LP>();
        __builtin_amdgcn_s_barrier();
        __builtin_amdgcn_sched_barrier(0);

        const int slot = p & 3;
        const unsigned short* as = lds + slot * ASLICE;
        const unsigned short* bs = lds + BOFF + slot * BSLICE;

        f16x8 af[MR], bf[NRW];
        #pragma unroll
        for (int n = 0; n < NRW; ++n) {
            int r = wc * (BN / WN) + n * 16 + fr;
            int es = fq ^ ((r >> 1) & 3);
            bf[n] = *(const f16x8*)&bs[r * 32 + es * 8];
        }
        #pragma unroll
        for (int m = 0; m < MH; ++m) {
            int r = wr * (BM / WM) + m * 16 + fr;
            int es = fq ^ ((r >> 1) & 3);
            af[m] = *(const f16x8*)&as[r * 32 + es * 8];
        }
        if (p + 3 < NPAIR) stage(p + 3);   // WAR-safe: slot (p+3)&3 == (p-1)&3;
                                           // all reads of p-1 done before barrier p
        // ph1 A-reads issue now; they complete under ph0's MFMA
        #pragma unroll
        for (int m = MH; m < MR; ++m) {
            int r = wr * (BM / WM) + m * 16 + fr;
            int es = fq ^ ((r >> 1) & 3);
            af[m] = *(const f16x8*)&as[r * 32 + es * 8];
        }

        waitlgkm<MR - MH>();               // ph0's 8 reads done; ph1's in flight
        __builtin_amdgcn_sched_barrier(0);
        __builtin_amdgcn_s_setprio(1);
        #pragma unroll
        for (int m = 0; m < MH; ++m)
            #pragma unroll
            for (int n = 0; n < NRW; ++n)
                acc[m][n] = __builtin_amdgcn_mfma_f32_16x16x32_f16(af[m], bf[n], acc[m][n], 0, 0, 0);
        __builtin_amdgcn_s_setprio(0);
        __builtin_amdgcn_sched_barrier(0);
        waitlgkm<0>();
        __builtin_amdgcn_sched_barrier(0);
        __builtin_amdgcn_s_setprio(1);
        #pragma unroll
        for (int m = MH; m < MR; ++m)
            #pragma unroll
            for (int n = 0; n < NRW; ++n)
                acc[m][n] = __builtin_amdgcn_mfma_f32_16x16x32_f16(af[m], bf[n], acc[m][n], 0, 0, 0);
        __builtin_amdgcn_s_setprio(0);
    }

    // epilogue: C/D layout col=lane&15, row=(lane>>4)*4+i
    const int row0 = by * BM + wr * (BM / WM);
    const int col0 = bx * BN + wc * (BN / WN);
    #pragma unroll
    for (int m = 0; m < MR; ++m)
        #pragma unroll
        for (int n = 0; n < NRW; ++n)
            #pragma unroll
            for (int i = 0; i < 4; ++i) {
                int r = row0 + m * 16 + fq * 4 + i;
                int c = col0 + n * 16 + fr;
                float v = acc[m][n][i];
                if constexpr (BIAS_MODE == 1) v += bias[c];
                if constexpr (BIAS_MODE == 2) v += bias[r];
                if constexpr (OUT_F16)
                    ((unsigned short*)Cptr + bz * cBatch)[(long long)r * ldc + c] = f2h_bits(v);
                else
                    ((float*)Cptr + bz * cBatch)[(long long)r * ldc + c] = v;
            }
}

// ===================== small kernels =====================
__global__ __launch_bounds__(256) void cvt_f32_f16(const float* __restrict__ in,
                                                   unsigned short* __restrict__ out, int n8)
{
    int i = blockIdx.x * blockDim.x + threadIdx.x;
    if (i >= n8) return;
    const float4* p = (const float4*)in + (long long)i * 2;
    float4 a = p[0], b = p[1];
    ushort4 o0, o1;
    o0.x = f2h_bits(a.x); o0.y = f2h_bits(a.y); o0.z = f2h_bits(a.z); o0.w = f2h_bits(a.w);
    o1.x = f2h_bits(b.x); o1.y = f2h_bits(b.y); o1.z = f2h_bits(b.z); o1.w = f2h_bits(b.w);
    ushort4* o = (ushort4*)out + (long long)i * 2;
    o[0] = o0; o[1] = o1;
}

__global__ void transpose_cvt(const float* __restrict__ in, unsigned short* __restrict__ out,
                              int R, int C)
{
    __shared__ unsigned short t[32][33];
    const int bx = blockIdx.x * 32;
    const int by = blockIdx.y * 32;
    const int xT = threadIdx.x, yT = threadIdx.y;  // block (32,8)
    #pragma unroll
    for (int i = 0; i < 32; i += 8)
        t[yT + i][xT] = f2h_bits(in[(long long)(by + yT + i) * C + bx + xT]);
    __syncthreads();
    #pragma unroll
    for (int i = 0; i < 32; i += 8)
        out[(long long)(bx + yT + i) * R + by + xT] = t[xT][yT + i];
}

__global__ void concat_bias2(const float* __restrict__ bq, const float* __restrict__ bk,
                             float* __restrict__ cb)
{
    int i = threadIdx.x;  // 1024 threads
    cb[i] = bq[i];
    cb[HIDDEN + i] = bk[i];
}

// One block (256 threads) per row of 2048 fp16 scores; P fp16 in place.
__global__ __launch_bounds__(256) void softmax_h(unsigned short* __restrict__ S)
{
    const int tid = threadIdx.x;
    unsigned short* row = S + (long long)blockIdx.x * SEQ;
    u16x8 hv = *(const u16x8*)&row[tid * 8];
    float vv[8];
    #pragma unroll
    for (int j = 0; j < 8; ++j) vv[j] = h2f(hv[j]);

    float mx = vv[0];
    #pragma unroll
    for (int j = 1; j < 8; ++j) mx = fmaxf(mx, vv[j]);
    #pragma unroll
    for (int o = 32; o > 0; o >>= 1) mx = fmaxf(mx, __shfl_xor(mx, o));
    __shared__ float redm[4], reds[4];
    if ((tid & 63) == 0) redm[tid >> 6] = mx;
    __syncthreads();
    mx = fmaxf(fmaxf(redm[0], redm[1]), fmaxf(redm[2], redm[3]));

    float ev[8], sum = 0.f;
    #pragma unroll
    for (int j = 0; j < 8; ++j) { ev[j] = __expf(vv[j] - mx); sum += ev[j]; }
    #pragma unroll
    for (int o = 32; o > 0; o >>= 1) sum += __shfl_xor(sum, o);
    if ((tid & 63) == 0) reds[tid >> 6] = sum;
    __syncthreads();
    sum = reds[0] + reds[1] + reds[2] + reds[3];
    float inv = 1.0f / sum;

    u16x8 ov;
    #pragma unroll
    for (int j = 0; j < 8; ++j) ov[j] = f2h_bits(ev[j] * inv);
    *(u16x8*)&row[tid * 8] = ov;
}

// ===================== launch =====================
extern "C" void kernel_launch(void* const* d_in, const int* in_sizes, int n_in,
                              void* d_out, int out_size, void* d_ws, size_t ws_size,
                              hipStream_t stream)
{
    (void)in_sizes; (void)n_in; (void)out_size; (void)ws_size;
    const float* x  = (const float*)d_in[0];
    const float* Wq = (const float*)d_in[1];
    const float* bq = (const float*)d_in[2];
    const float* Wk = (const float*)d_in[3];
    const float* bk = (const float*)d_in[4];
    const float* Wv = (const float*)d_in[5];
    const float* bv = (const float*)d_in[6];
    float* out = (float*)d_out;

    // variants: proj/S 256x256 (8 waves, 128KB); vt 128x256 (96KB); O 256x128 (96KB)
    (void)hipFuncSetAttribute(reinterpret_cast<const void*>(&gemm8p<256, 256, 2, 4, 1, true, 2>),
                              hipFuncAttributeMaxDynamicSharedMemorySize, 131072);
    (void)hipFuncSetAttribute(reinterpret_cast<const void*>(&gemm8p<256, 256, 2, 4, 0, true, 2>),
                              hipFuncAttributeMaxDynamicSharedMemorySize, 131072);
    (void)hipFuncSetAttribute(reinterpret_cast<const void*>(&gemm8p<128, 256, 2, 4, 2, true, 2>),
                              hipFuncAttributeMaxDynamicSharedMemorySize, 98304);
    (void)hipFuncSetAttribute(reinterpret_cast<const void*>(&gemm8p<256, 128, 2, 4, 0, false, 2>),
                              hipFuncAttributeMaxDynamicSharedMemorySize, 98304);

    char* ws = (char*)d_ws;
    const long long MTOT = (long long)NB * SEQ;  // 8192

    // Layout (83.9 MB):
    //  [0, 33.55M)      qk   [8192][2048] fp16
    //  [33.55, 50.33M)  vt   [1024][8192] fp16
    //  [50.33, 83.89M)  S region: 4 x [2048][2048] fp16 (all batches).
    //    During projections it holds wt (6.29M) + cb + xh (16.78M), dead after vt.
    unsigned short* qk = (unsigned short*)ws;
    unsigned short* vt = (unsigned short*)(ws + (size_t)MTOT * 2048 * 2);
    char* sreg = ws + (size_t)MTOT * 2048 * 2 + (size_t)HIDDEN * MTOT * 2;
    unsigned short* wt = (unsigned short*)sreg;
    float* cb = (float*)(sreg + (size_t)3 * HIDDEN * HIDDEN * 2);
    unsigned short* xh = (unsigned short*)(sreg + (size_t)3 * HIDDEN * HIDDEN * 2 + 8192);
    unsigned short* S = (unsigned short*)sreg;

    {
        int n8 = (int)(MTOT * HIDDEN / 8);
        cvt_f32_f16<<<dim3((n8 + 255) / 256), 256, 0, stream>>>(x, xh, n8);
    }
    dim3 tb(32, 8), tg(HIDDEN / 32, HIDDEN / 32);
    transpose_cvt<<<tg, tb, 0, stream>>>(Wq, wt,                       HIDDEN, HIDDEN);
    transpose_cvt<<<tg, tb, 0, stream>>>(Wk, wt +     HIDDEN * HIDDEN, HIDDEN, HIDDEN);
    transpose_cvt<<<tg, tb, 0, stream>>>(Wv, wt + 2 * HIDDEN * HIDDEN, HIDDEN, HIDDEN);
    concat_bias2<<<1, 1024, 0, stream>>>(bq, bk, cb);

    // qk[8192][2048] = xh @ [Wq|Wk] + [bq|bk]   (256 blocks)
    gemm8p<256, 256, 2, 4, 1, true, 2><<<dim3(2048 / 256, (unsigned)(MTOT / 256), 1), 512, 131072, stream>>>(
        xh, HIDDEN, wt, HIDDEN, cb, qk, 2048, HIDDEN, 0, 0, 0);

    // vt[1024][8192] = Wv^T @ xh^T + bv (row bias)   (256 blocks)
    gemm8p<128, 256, 2, 4, 2, true, 2><<<dim3((unsigned)(MTOT / 256), HIDDEN / 128, 1), 512, 98304, stream>>>(
        wt + 2 * HIDDEN * HIDDEN, HIDDEN, xh, HIDDEN, bv, vt, (int)MTOT, HIDDEN, 0, 0, 0);

    // S[b][2048][2048] fp16 = q @ k^T   (z=4, 256 blocks)
    gemm8p<256, 256, 2, 4, 0, true, 2><<<dim3(SEQ / 256, SEQ / 256, NB), 512, 131072, stream>>>(
        qk, 2048, qk + HIDDEN, 2048, nullptr, S, SEQ, HIDDEN,
        (long long)SEQ * 2048, (long long)SEQ * 2048, (long long)SEQ * SEQ);

    // softmax all rows, P fp16 in place
    softmax_h<<<dim3(NB * SEQ), 256, 0, stream>>>(S);

    // out[b] = P @ vt^T  (z=4, 512 blocks, f32 straight to d_out)
    gemm8p<256, 128, 2, 4, 0, false, 2><<<dim3(HIDDEN / 128, SEQ / 256, NB), 512, 98304, stream>>>(
        S, SEQ, vt, (int)MTOT, nullptr, out, HIDDEN, SEQ,
        (long long)SEQ * SEQ, (long long)SEQ, (long long)SEQ * HIDDEN);
}